// Round 5
// baseline (95.315 us; speedup 1.0000x reference)
//
#include <hip/hip_runtime.h>

// Concordance index, status-partitioned + padded formulation.
// answer = (CC_full - K) / (TP_full - K), K = #(status==1), le == !ge
// (distinct values — verified: absmax 0.0 in rounds 2-4).
//   region (1,1): cc = (ge==geh), tp = 1      -> tp analytic K^2
//   region (0,1) == (1,0) transposed          -> compute once, double
//   region (0,0): contributes nothing         -> skipped
// CC_full = [Kp^2 - NE - (Kp-K)^2] + 2*BC ;  TP_full = K^2 + 2*BG
// Arrays padded to Kp/Mp (multiples of 1024) with sentinels:
//   st1 pad = (+inf,-inf): vs real -> ne=1 (absorbed); pad-vs-pad -> eq=1,
//   exactly (Kp-K)^2 spurious, subtracted analytically.
//   st0 pad = (-inf,-inf): ge always false -> contributes 0 to BG/BC.
// => pairs kernel has NO edge handling: compile-time trip counts, uniform
// control flow, float2 LDS broadcast reads (R3 lesson).

#define BLOCK 256
#define TJ 256
#define IT 4
#define TI (BLOCK * IT)          // 1024
#define GRID_PAIRS 1024

// ws: [0] u32 cnts[2] (K, M); [8] ull acc[3] (NE, BC, BG); [64] float2 p1[stride], p0[stride]

__global__ __launch_bounds__(256) void fill_kernel(
    float2* __restrict__ p1, float2* __restrict__ p0, int stride,
    unsigned* __restrict__ hdr)
{
    int i = blockIdx.x * 256 + threadIdx.x;
    if (i < stride) {
        p1[i] = make_float2(__int_as_float(0x7f800000), __int_as_float(0xff800000));
        p0[i] = make_float2(__int_as_float(0xff800000), __int_as_float(0xff800000));
    }
    if (blockIdx.x == 0 && threadIdx.x < 8) hdr[threadIdx.x] = 0u;  // cnts + acc
}

__global__ __launch_bounds__(256) void compact_kernel(
    const float* __restrict__ y, const float* __restrict__ yh,
    const int* __restrict__ status, int n,
    unsigned* __restrict__ cnts,
    float2* __restrict__ p1, float2* __restrict__ p0)
{
    int i = blockIdx.x * 256 + threadIdx.x;
    int lane = threadIdx.x & 63;
    bool act = i < n;
    float yv  = act ? y[i]  : 0.0f;
    float yhv = act ? yh[i] : 0.0f;
    bool st = act && (status[i] == 1);
    unsigned long long m1 = __ballot(st);
    unsigned long long m0 = __ballot(act && !st);
    unsigned long long lt = (1ull << lane) - 1ull;
    unsigned b1 = 0, b0 = 0;
    if (lane == 0) {
        b1 = atomicAdd(&cnts[0], (unsigned)__popcll(m1));
        b0 = atomicAdd(&cnts[1], (unsigned)__popcll(m0));
    }
    b1 = __shfl(b1, 0, 64);
    b0 = __shfl(b0, 0, 64);
    if (st) {
        p1[b1 + (unsigned)__popcll(m1 & lt)] = make_float2(yv, yhv);
    } else if (act) {
        p0[b0 + (unsigned)__popcll(m0 & lt)] = make_float2(yv, yhv);
    }
}

__global__ __launch_bounds__(BLOCK) void pairs_kernel(
    const unsigned* __restrict__ cnts,
    const float2* __restrict__ p1, const float2* __restrict__ p0,
    unsigned long long* __restrict__ acc)
{
    __shared__ float2 s_j[TJ];
    const int tid = threadIdx.x;
    const unsigned K = cnts[0], M = cnts[1];
    const int Kp = (int)((K + 1023u) & ~1023u);
    const int Mp = (int)((M + 1023u) & ~1023u);
    const int ntJ  = Kp >> 8;    // Kp / TJ
    const int ntIA = Kp >> 10;   // Kp / TI
    const int ntIB = Mp >> 10;   // Mp / TI
    const int ntA  = ntIA * ntJ;
    const int ntot = ntA + ntIB * ntJ;

    unsigned accNE = 0, accBC = 0, accBG = 0;

    for (int t = blockIdx.x; t < ntot; t += gridDim.x) {
        bool isA = t < ntA;
        int tt = isA ? t : t - ntA;
        int ti = tt / ntJ;
        int tj = tt - ti * ntJ;

        s_j[tid] = p1[tj * TJ + tid];          // j always from st1 set
        __syncthreads();

        const float2* pi = isA ? p1 : p0;
        int ib = ti * TI + tid;
        float2 v0 = pi[ib];
        float2 v1 = pi[ib + BLOCK];
        float2 v2 = pi[ib + 2 * BLOCK];
        float2 v3 = pi[ib + 3 * BLOCK];

        if (isA) {
            unsigned n0 = 0, n1 = 0;
#pragma unroll 8
            for (int jj = 0; jj < TJ; ++jj) {
                float2 p = s_j[jj];
                n0 += (unsigned)((v0.x >= p.x) != (v0.y >= p.y));
                n1 += (unsigned)((v1.x >= p.x) != (v1.y >= p.y));
                n0 += (unsigned)((v2.x >= p.x) != (v2.y >= p.y));
                n1 += (unsigned)((v3.x >= p.x) != (v3.y >= p.y));
            }
            accNE += n0 + n1;
        } else {
            unsigned g0 = 0, g1 = 0, c0 = 0, c1 = 0;
#pragma unroll 8
            for (int jj = 0; jj < TJ; ++jj) {
                float2 p = s_j[jj];
                bool a0 = v0.x >= p.x, b0 = v0.y >= p.y;
                bool a1 = v1.x >= p.x, b1 = v1.y >= p.y;
                bool a2 = v2.x >= p.x, b2 = v2.y >= p.y;
                bool a3 = v3.x >= p.x, b3 = v3.y >= p.y;
                g0 += (unsigned)a0; c0 += (unsigned)(a0 & b0);
                g1 += (unsigned)a1; c1 += (unsigned)(a1 & b1);
                g0 += (unsigned)a2; c0 += (unsigned)(a2 & b2);
                g1 += (unsigned)a3; c1 += (unsigned)(a3 & b3);
            }
            accBG += g0 + g1; accBC += c0 + c1;
        }
        __syncthreads();
    }

    // wave shuffle -> LDS -> 3 atomics per block
#pragma unroll
    for (int off = 32; off > 0; off >>= 1) {
        accNE += __shfl_down(accNE, off, 64);
        accBC += __shfl_down(accBC, off, 64);
        accBG += __shfl_down(accBG, off, 64);
    }
    __shared__ unsigned rN[4], rC[4], rG[4];
    int wav = tid >> 6, lane = tid & 63;
    if (lane == 0) { rN[wav] = accNE; rC[wav] = accBC; rG[wav] = accBG; }
    __syncthreads();
    if (tid == 0) {
        unsigned long long ne = (unsigned long long)rN[0] + rN[1] + rN[2] + rN[3];
        unsigned long long bc = (unsigned long long)rC[0] + rC[1] + rC[2] + rC[3];
        unsigned long long bg = (unsigned long long)rG[0] + rG[1] + rG[2] + rG[3];
        if (ne) atomicAdd(&acc[0], ne);
        if (bc) atomicAdd(&acc[1], bc);
        if (bg) atomicAdd(&acc[2], bg);
    }
}

__global__ void finalize_kernel(const unsigned* __restrict__ cnts,
                                const unsigned long long* __restrict__ acc,
                                float* __restrict__ out)
{
    if (threadIdx.x == 0) {
        unsigned long long K = cnts[0];
        unsigned long long Kp = (K + 1023ull) & ~1023ull;
        unsigned long long pad = Kp - K;
        unsigned long long CC = Kp * Kp - acc[0] - pad * pad + 2ull * acc[1];
        unsigned long long TP = K * K + 2ull * acc[2];
        long long cn = (long long)CC - (long long)K;
        long long tn = (long long)TP - (long long)K;
        out[0] = (float)cn / (float)tn;
    }
}

extern "C" void kernel_launch(void* const* d_in, const int* in_sizes, int n_in,
                              void* d_out, int out_size, void* d_ws, size_t ws_size,
                              hipStream_t stream) {
    const float* y      = (const float*)d_in[0];
    const float* y_hat  = (const float*)d_in[1];
    const int*   status = (const int*)d_in[2];
    float* out = (float*)d_out;
    int n = in_sizes[0];
    int stride = n + 1024;   // room for pad-rounding to x1024

    char* base = (char*)d_ws;
    unsigned* cnts = (unsigned*)base;
    unsigned long long* acc = (unsigned long long*)(base + 8);
    float2* p1 = (float2*)(base + 64);
    float2* p0 = p1 + stride;

    hipLaunchKernelGGL(fill_kernel, dim3((stride + 255) / 256), dim3(256), 0, stream,
                       p1, p0, stride, cnts);

    hipLaunchKernelGGL(compact_kernel, dim3((n + 255) / 256), dim3(256), 0, stream,
                       y, y_hat, status, n, cnts, p1, p0);

    hipLaunchKernelGGL(pairs_kernel, dim3(GRID_PAIRS), dim3(BLOCK), 0, stream,
                       cnts, p1, p0, acc);

    hipLaunchKernelGGL(finalize_kernel, dim3(1), dim3(64), 0, stream,
                       cnts, acc, out);
}